// Round 3
// baseline (547.024 us; speedup 1.0000x reference)
//
#include <hip/hip_runtime.h>

typedef __bf16 bf16_t;
typedef __bf16 bf16x8 __attribute__((ext_vector_type(8)));
typedef __bf16 bf16x4 __attribute__((ext_vector_type(4)));
typedef float  f32x4  __attribute__((ext_vector_type(4)));

#define HW_ 65536
#define C_  128

// XOR swizzle: spread 16B slots (byte bits [6:4]) by row index.
__device__ __forceinline__ int swz(int r) { return ((r ^ (r >> 3)) & 7) << 4; }

#define LGKM0() asm volatile("s_waitcnt lgkmcnt(0)" ::: "memory")
__device__ __forceinline__ void BAR() {
  asm volatile("" ::: "memory");
  __builtin_amdgcn_s_barrier();
  asm volatile("" ::: "memory");
}

// =====================================================================
// Phase 1: map = PReLU(W*x + b).  Per-b GEMM M=128(o),K=128(c),N=128(s)/WG.
// LDS: Xs [0,32K): x-tile transposed bf16, byte(s,c)=(s*256+c*2)^swz(s)
//      Ws [32K,64K): weights, then reused as bounce buffer for the epilogue.
// Epilogue: acc -> LDS [o][s] bf16 -> b128 reads -> 16B/lane global stores.
// HBLK: mH W32-blocked layout [c][w>>5][h][w&31] for attn's PV A-reads.
// =====================================================================
template<bool HBLK>
__device__ __forceinline__ void conv_one(char* lds, const float* __restrict__ Wsrc,
                                         const float* __restrict__ bias, float alpha,
                                         bf16_t* __restrict__ dst, size_t pb,
                                         int wv, int lr, int lq, int t, int s0)
{
  BAR();  // prev bounce readers done; Ws region free
  #pragma unroll
  for (int rep = 0; rep < 16; ++rep) {
    int q = rep * 256 + t;
    int o = q >> 5, c0 = (q & 31) * 4;
    f32x4 w4 = *(const f32x4*)(Wsrc + o * C_ + c0);
    bf16x4 v;
    v[0] = (bf16_t)w4[0]; v[1] = (bf16_t)w4[1]; v[2] = (bf16_t)w4[2]; v[3] = (bf16_t)w4[3];
    *(bf16x4*)(lds + 32768 + ((o * 256 + c0 * 2) ^ swz(o))) = v;
  }
  LGKM0(); BAR();

  const f32x4 fz = {0.f, 0.f, 0.f, 0.f};
  f32x4 acc[2][8];
  #pragma unroll
  for (int mf = 0; mf < 2; ++mf)
    #pragma unroll
    for (int nf = 0; nf < 8; ++nf)
      acc[mf][nf] = fz;

  #pragma unroll
  for (int ks = 0; ks < 4; ++ks) {
    int kb = ks * 32 + lq * 8;
    bf16x8 a[2], bb[8];
    #pragma unroll
    for (int mf = 0; mf < 2; ++mf) {
      int m = wv * 32 + mf * 16 + lr;
      a[mf] = *(const bf16x8*)(lds + 32768 + ((m * 256 + kb * 2) ^ swz(m)));
    }
    #pragma unroll
    for (int nf = 0; nf < 8; ++nf) {
      int n = nf * 16 + lr;
      bb[nf] = *(const bf16x8*)(lds + ((n * 256 + kb * 2) ^ swz(n)));
    }
    #pragma unroll
    for (int mf = 0; mf < 2; ++mf)
      #pragma unroll
      for (int nf = 0; nf < 8; ++nf)
        acc[mf][nf] = __builtin_amdgcn_mfma_f32_16x16x32_bf16(a[mf], bb[nf], acc[mf][nf], 0, 0, 0);
  }

  BAR();  // all waves done reading Ws -> reuse as bounce buffer

  // bounce write: bias + PReLU + bf16 -> LDS [o][s], swizzled 16B slots
  #pragma unroll
  for (int mf = 0; mf < 2; ++mf) {
    #pragma unroll
    for (int i = 0; i < 4; ++i) {
      int o = wv * 32 + mf * 16 + lq * 4 + i;
      float bo = bias[o];
      #pragma unroll
      for (int nf = 0; nf < 8; ++nf) {
        int s = nf * 16 + lr;
        float v = acc[mf][nf][i] + bo;
        v = (v >= 0.f) ? v : alpha * v;
        *(bf16_t*)(lds + 32768 + ((o * 256 + s * 2) ^ ((o & 7) << 4))) = (bf16_t)v;
      }
    }
  }
  LGKM0(); BAR();

  // bounce read: b128 per thread, 16B/lane coalesced global stores
  const int h_ = s0 >> 8, w0_ = s0 & 255;
  #pragma unroll
  for (int r = 0; r < 8; ++r) {
    int q = r * 256 + t;
    int o = q >> 4, sc = q & 15;
    bf16x8 vv = *(const bf16x8*)(lds + 32768 + ((o * 256 + sc * 16) ^ ((o & 7) << 4)));
    size_t off;
    if (HBLK) {
      int w = w0_ + sc * 8;
      off = pb + (size_t)o * HW_ + (size_t)(w >> 5) * 8192 + h_ * 32 + (w & 31);
    } else {
      off = pb + (size_t)o * HW_ + s0 + sc * 8;
    }
    *(bf16x8*)(dst + off) = vv;
  }
}

__global__ __launch_bounds__(256, 2) void conv_kernel(
    const float* __restrict__ x,
    const float* __restrict__ Wf, const float* __restrict__ bfp, const float* __restrict__ afp,
    const float* __restrict__ Wg, const float* __restrict__ bgp, const float* __restrict__ agp,
    const float* __restrict__ Wh, const float* __restrict__ bhp, const float* __restrict__ ahp,
    bf16_t* __restrict__ mF, bf16_t* __restrict__ mG, bf16_t* __restrict__ mH, int b0)
{
  __shared__ __align__(16) char lds[65536];
  const int t = threadIdx.x;
  const int bloc = blockIdx.y;
  const int s0 = blockIdx.x * 128;
  const size_t xbase = ((size_t)(b0 + bloc) * C_) * HW_ + s0;

  // stage x tile (128c x 128s) f32 -> transposed bf16 LDS [s][c]
  #pragma unroll
  for (int rep = 0; rep < 4; ++rep) {
    int q = rep * 256 + t;
    int c0 = (q >> 5) * 4, sl0 = (q & 31) * 4;
    f32x4 r[4];
    #pragma unroll
    for (int i = 0; i < 4; ++i)
      r[i] = *(const f32x4*)(x + xbase + (size_t)(c0 + i) * HW_ + sl0);
    #pragma unroll
    for (int js = 0; js < 4; ++js) {
      int s = sl0 + js;
      bf16x4 v;
      v[0] = (bf16_t)r[0][js]; v[1] = (bf16_t)r[1][js];
      v[2] = (bf16_t)r[2][js]; v[3] = (bf16_t)r[3][js];
      *(bf16x4*)(lds + ((s * 256 + c0 * 2) ^ swz(s))) = v;
    }
  }

  const int wv = t >> 6, lane = t & 63, lr = lane & 15, lq = lane >> 4;
  const size_t pb = (size_t)bloc * C_ * HW_;
  conv_one<false>(lds, Wf, bfp, afp[0], mF, pb, wv, lr, lq, t, s0);
  conv_one<false>(lds, Wg, bgp, agp[0], mG, pb, wv, lr, lq, t, s0);
  conv_one<true >(lds, Wh, bhp, ahp[0], mH, pb, wv, lr, lq, t, s0);
}

// =====================================================================
// Phase 2: 1024 thr / 16 waves, per (b,c) plane.
//  S phase  : wave split (wr4 x wc4), S acc 64 f32/lane, raw barriers so
//             the next-chunk global prefetch stays in flight (vmcnt alive).
//  softmax  : 4-group cross-wave combine via smax/ssum overlaid in PT region.
//  PV phase : wave re-split (wr8 x wc2); A = H direct from global
//             (W32-blocked, 1KB contiguous per wave-read, unique per wr8,
//             3-deep pipeline); B = PT bf16 LDS; ZERO barriers in loop.
// LDS (131072 B): [0,64K) Ft|Gt chunks -> reused as PT[v=256][w=256] bf16;
//                 smax f32[4][256] @0, ssum @4096 (dead before PT writes).
// =====================================================================
#define ATTN_SMEM 131072

__global__ __launch_bounds__(1024, 4) void attn_kernel(
    const bf16_t* __restrict__ mF, const bf16_t* __restrict__ mG, const bf16_t* __restrict__ mH,
    const float* __restrict__ x, float* __restrict__ out, int b0)
{
  extern __shared__ __align__(16) char smem[];
  const int t = threadIdx.x;
  const int c = blockIdx.x, bloc = blockIdx.y;
  const int lane = t & 63, lr = lane & 15, lq = lane >> 4;
  const int wv = t >> 6;
  const int wr4 = wv >> 2, wc4 = wv & 3;     // S-phase split
  const int wr8 = wv >> 1, wc2 = wv & 1;     // PV-phase split
  const size_t plane  = ((size_t)bloc * C_ + c) * HW_;
  const size_t gplane = (((size_t)(b0 + bloc)) * C_ + c) * HW_;

  const f32x4 fz = {0.f, 0.f, 0.f, 0.f};
  f32x4 acc[4][4];
  #pragma unroll
  for (int mf = 0; mf < 4; ++mf)
    #pragma unroll
    for (int nf = 0; nf < 4; ++nf)
      acc[mf][nf] = fz;

  // ---- S = F^T G, 4 h-chunks of 64 ----
  const int sg = t >> 9;             // waves 0..7 stage F, 8..15 stage G
  const int u  = t & 511;
  const int w0 = (u & 31) * 8, h0 = (u >> 5) * 4;
  const bf16_t* sp = sg ? mG : mF;
  char* sd = smem + sg * 32768;

  bf16x8 pf[4];
  #pragma unroll
  for (int i = 0; i < 4; ++i)
    pf[i] = *(const bf16x8*)(sp + plane + (size_t)(h0 + i) * 256 + w0);

  #pragma unroll
  for (int hc = 0; hc < 4; ++hc) {
    #pragma unroll
    for (int j = 0; j < 8; ++j) {
      int w = w0 + j;
      bf16x4 v; v[0] = pf[0][j]; v[1] = pf[1][j]; v[2] = pf[2][j]; v[3] = pf[3][j];
      *(bf16x4*)(sd + ((w * 128 + h0 * 2) ^ swz(w))) = v;
    }
    if (hc < 3) {                    // prefetch next chunk; raw barrier keeps it in flight
      #pragma unroll
      for (int i = 0; i < 4; ++i)
        pf[i] = *(const bf16x8*)(sp + plane + (size_t)((hc + 1) * 64 + h0 + i) * 256 + w0);
    }
    LGKM0(); BAR();
    #pragma unroll
    for (int k0 = 0; k0 < 64; k0 += 32) {
      const int kb = k0 + lq * 8;
      bf16x8 af[4], bq[4];
      #pragma unroll
      for (int mf = 0; mf < 4; ++mf) {
        int m = wr4 * 64 + mf * 16 + lr;
        af[mf] = *(const bf16x8*)(smem + ((m * 128 + kb * 2) ^ swz(m)));
      }
      #pragma unroll
      for (int nf = 0; nf < 4; ++nf) {
        int n = wc4 * 64 + nf * 16 + lr;
        bq[nf] = *(const bf16x8*)(smem + 32768 + ((n * 128 + kb * 2) ^ swz(n)));
      }
      #pragma unroll
      for (int mf = 0; mf < 4; ++mf)
        #pragma unroll
        for (int nf = 0; nf < 4; ++nf)
          acc[mf][nf] = __builtin_amdgcn_mfma_f32_16x16x32_bf16(af[mf], bq[nf], acc[mf][nf], 0, 0, 0);
    }
    BAR();
  }

  // ---- softmax over v (rows w) ----
  float* smax = (float*)smem;
  float* ssum = (float*)(smem + 4096);
  float rinv[4][4];
  {
    float rowm[4][4];
    #pragma unroll
    for (int mf = 0; mf < 4; ++mf)
      #pragma unroll
      for (int i = 0; i < 4; ++i) {
        float m = fmaxf(fmaxf(acc[mf][0][i], acc[mf][1][i]),
                        fmaxf(acc[mf][2][i], acc[mf][3][i]));
        #pragma unroll
        for (int d = 1; d < 16; d <<= 1) m = fmaxf(m, __shfl_xor(m, d));
        rowm[mf][i] = m;
      }
    if (lr == 0) {
      #pragma unroll
      for (int mf = 0; mf < 4; ++mf)
        #pragma unroll
        for (int i = 0; i < 4; ++i)
          smax[wc4 * 256 + wr4 * 64 + mf * 16 + lq * 4 + i] = rowm[mf][i];
    }
    LGKM0(); BAR();
    #pragma unroll
    for (int mf = 0; mf < 4; ++mf)
      #pragma unroll
      for (int i = 0; i < 4; ++i) {
        int w = wr4 * 64 + mf * 16 + lq * 4 + i;
        rowm[mf][i] = fmaxf(fmaxf(smax[w], smax[256 + w]),
                            fmaxf(smax[512 + w], smax[768 + w]));
      }
    #pragma unroll
    for (int mf = 0; mf < 4; ++mf)
      #pragma unroll
      for (int i = 0; i < 4; ++i) {
        float rs = 0.f;
        #pragma unroll
        for (int nf = 0; nf < 4; ++nf) {
          float e = __expf(acc[mf][nf][i] - rowm[mf][i]);
          acc[mf][nf][i] = e;
          rs += e;
        }
        #pragma unroll
        for (int d = 1; d < 16; d <<= 1) rs += __shfl_xor(rs, d);
        if (lr == 0) ssum[wc4 * 256 + wr4 * 64 + mf * 16 + lq * 4 + i] = rs;
      }
    LGKM0(); BAR();
    #pragma unroll
    for (int mf = 0; mf < 4; ++mf)
      #pragma unroll
      for (int i = 0; i < 4; ++i) {
        int w = wr4 * 64 + mf * 16 + lq * 4 + i;
        rinv[mf][i] = 1.f / (ssum[w] + ssum[256 + w] + ssum[512 + w] + ssum[768 + w]);
      }
    BAR();  // all smax/ssum reads done before PT overwrites [0,8K)
  }

  // ---- P -> bf16 -> PT[v][w] ----
  #pragma unroll
  for (int mf = 0; mf < 4; ++mf) {
    int wpb = (wr4 * 64 + mf * 16 + lq * 4) * 2;
    #pragma unroll
    for (int nf = 0; nf < 4; ++nf) {
      int v_ = wc4 * 64 + nf * 16 + lr;
      bf16x4 v;
      #pragma unroll
      for (int i = 0; i < 4; ++i) v[i] = (bf16_t)(acc[mf][nf][i] * rinv[mf][i]);
      *(bf16x4*)(smem + ((v_ * 512 + wpb) ^ swz(v_))) = v;
    }
  }

  // ---- prefetch H chunks 0..2 (W32-blocked, 1KB contiguous per wave-read) ----
  const bf16_t* hp = mH + plane;
  bf16x8 aP[3][2];
  #pragma unroll
  for (int p = 0; p < 3; ++p)
    #pragma unroll
    for (int mf = 0; mf < 2; ++mf) {
      int h = wr8 * 32 + mf * 16 + lr;
      aP[p][mf] = *(const bf16x8*)(hp + p * 8192 + h * 32 + lq * 8);
    }

  LGKM0(); BAR();  // PT visible to all; H prefetch stays in flight

  // ---- out = H*P: 8 w-chunks, no barriers ----
  f32x4 oac[2][8];
  #pragma unroll
  for (int mf = 0; mf < 2; ++mf)
    #pragma unroll
    for (int nf = 0; nf < 8; ++nf)
      oac[mf][nf] = fz;

  #pragma unroll
  for (int k = 0; k < 8; ++k) {
    #pragma unroll
    for (int h2 = 0; h2 < 2; ++h2) {
      bf16x8 bq[4];
      #pragma unroll
      for (int nf = 0; nf < 4; ++nf) {
        int v_ = wc2 * 128 + (h2 * 4 + nf) * 16 + lr;
        bq[nf] = *(const bf16x8*)(smem + ((v_ * 512 + k * 64 + lq * 16) ^ swz(v_)));
      }
      #pragma unroll
      for (int mf = 0; mf < 2; ++mf)
        #pragma unroll
        for (int nf = 0; nf < 4; ++nf)
          oac[mf][h2 * 4 + nf] =
            __builtin_amdgcn_mfma_f32_16x16x32_bf16(aP[k % 3][mf], bq[nf], oac[mf][h2 * 4 + nf], 0, 0, 0);
    }
    if (k < 5) {
      #pragma unroll
      for (int mf = 0; mf < 2; ++mf) {
        int h = wr8 * 32 + mf * 16 + lr;
        aP[k % 3][mf] = *(const bf16x8*)(hp + (size_t)(k + 3) * 8192 + h * 32 + lq * 8);
      }
    }
  }

  // ---- residual + store f32 ----
  #pragma unroll
  for (int mf = 0; mf < 2; ++mf)
    #pragma unroll
    for (int i = 0; i < 4; ++i) {
      int h = wr8 * 32 + mf * 16 + lq * 4 + i;
      #pragma unroll
      for (int nf = 0; nf < 8; ++nf) {
        int v_ = wc2 * 128 + nf * 16 + lr;
        size_t off = gplane + (size_t)h * 256 + v_;
        out[off] = oac[mf][nf][i] + x[off];
      }
    }
}

// =====================================================================
extern "C" void kernel_launch(void* const* d_in, const int* in_sizes, int n_in,
                              void* d_out, int out_size, void* d_ws, size_t ws_size,
                              hipStream_t stream)
{
  (void)in_sizes; (void)n_in; (void)out_size;
  const float* x   = (const float*)d_in[0];
  const float* Wf  = (const float*)d_in[1];
  const float* bfp = (const float*)d_in[2];
  const float* afp = (const float*)d_in[3];
  const float* Wg  = (const float*)d_in[4];
  const float* bgp = (const float*)d_in[5];
  const float* agp = (const float*)d_in[6];
  const float* Wh  = (const float*)d_in[7];
  const float* bhp = (const float*)d_in[8];
  const float* ahp = (const float*)d_in[9];
  float* out = (float*)d_out;

  const size_t per_map_b = (size_t)C_ * HW_ * sizeof(bf16_t);  // 16 MiB per map per batch
  int nb = 1;
  if      (ws_size >= 3 * 8 * per_map_b) nb = 8;
  else if (ws_size >= 3 * 4 * per_map_b) nb = 4;
  else if (ws_size >= 3 * 2 * per_map_b) nb = 2;

  hipFuncSetAttribute(reinterpret_cast<const void*>(attn_kernel),
                      hipFuncAttributeMaxDynamicSharedMemorySize, ATTN_SMEM);

  bf16_t* mF = (bf16_t*)d_ws;
  bf16_t* mG = mF + (size_t)nb * C_ * HW_;
  bf16_t* mH = mG + (size_t)nb * C_ * HW_;

  for (int b0 = 0; b0 < 8; b0 += nb) {
    conv_kernel<<<dim3(512, nb), 256, 0, stream>>>(x, Wf, bfp, afp, Wg, bgp, agp,
                                                   Wh, bhp, ahp, mF, mG, mH, b0);
    attn_kernel<<<dim3(C_, nb), 1024, ATTN_SMEM, stream>>>(mF, mG, mH, x, out, b0);
  }
}

// Round 4
// 534.174 us; speedup vs baseline: 1.0241x; 1.0241x over previous
//
#include <hip/hip_runtime.h>

typedef __bf16 bf16_t;
typedef __bf16 bf16x8 __attribute__((ext_vector_type(8)));
typedef __bf16 bf16x4 __attribute__((ext_vector_type(4)));
typedef float  f32x4  __attribute__((ext_vector_type(4)));

#define HW_ 65536
#define C_  128

// XOR swizzle: spread 16B slots (byte bits [6:4]) by row index.
__device__ __forceinline__ int swz(int r) { return ((r ^ (r >> 3)) & 7) << 4; }

#define LGKM0() asm volatile("s_waitcnt lgkmcnt(0)" ::: "memory")
__device__ __forceinline__ void BAR() {
  asm volatile("" ::: "memory");
  __builtin_amdgcn_s_barrier();
  asm volatile("" ::: "memory");
}

// =====================================================================
// Phase 1 (R1 form, known 154us): map = PReLU(W*x + b).
// GEMM M=128(o), K=128(c), N=128(spatial)/WG.  Direct 2B global stores.
// HBLK: mH W32-blocked [c][w>>5][h][w&31] for attn PV direct A-reads.
// =====================================================================
template<bool HBLK>
__device__ __forceinline__ void conv_one(char* lds, const float* __restrict__ Wsrc,
                                         const float* __restrict__ bias, float alpha,
                                         bf16_t* __restrict__ dst, size_t pb,
                                         int wv, int lr, int lq, int t, int s0)
{
  __syncthreads();
  #pragma unroll
  for (int rep = 0; rep < 16; ++rep) {
    int q = rep * 256 + t;
    int o = q >> 5, c0 = (q & 31) * 4;
    f32x4 w4 = *(const f32x4*)(Wsrc + o * C_ + c0);
    bf16x4 v;
    v[0] = (bf16_t)w4[0]; v[1] = (bf16_t)w4[1]; v[2] = (bf16_t)w4[2]; v[3] = (bf16_t)w4[3];
    *(bf16x4*)(lds + 32768 + ((o * 256 + c0 * 2) ^ swz(o))) = v;
  }
  __syncthreads();

  const f32x4 fz = {0.f, 0.f, 0.f, 0.f};
  f32x4 acc[2][8];
  #pragma unroll
  for (int mf = 0; mf < 2; ++mf)
    #pragma unroll
    for (int nf = 0; nf < 8; ++nf)
      acc[mf][nf] = fz;

  #pragma unroll
  for (int ks = 0; ks < 4; ++ks) {
    int kb = ks * 32 + lq * 8;
    bf16x8 a[2], bb[8];
    #pragma unroll
    for (int mf = 0; mf < 2; ++mf) {
      int m = wv * 32 + mf * 16 + lr;
      a[mf] = *(const bf16x8*)(lds + 32768 + ((m * 256 + kb * 2) ^ swz(m)));
    }
    #pragma unroll
    for (int nf = 0; nf < 8; ++nf) {
      int n = nf * 16 + lr;
      bb[nf] = *(const bf16x8*)(lds + ((n * 256 + kb * 2) ^ swz(n)));
    }
    #pragma unroll
    for (int mf = 0; mf < 2; ++mf)
      #pragma unroll
      for (int nf = 0; nf < 8; ++nf)
        acc[mf][nf] = __builtin_amdgcn_mfma_f32_16x16x32_bf16(a[mf], bb[nf], acc[mf][nf], 0, 0, 0);
  }

  // epilogue: bias + PReLU + direct bf16 stores (D: row=(l>>4)*4+i, col=l&15)
  #pragma unroll
  for (int mf = 0; mf < 2; ++mf) {
    #pragma unroll
    for (int i = 0; i < 4; ++i) {
      int o = wv * 32 + mf * 16 + lq * 4 + i;
      float bo = bias[o];
      #pragma unroll
      for (int nf = 0; nf < 8; ++nf) {
        int s = s0 + nf * 16 + lr;
        float v = acc[mf][nf][i] + bo;
        v = (v >= 0.f) ? v : alpha * v;
        size_t off;
        if (HBLK) {                       // W32-blocked [c][w>>5][h][w&31]
          int h = s >> 8, w = s & 255;
          off = pb + (size_t)o * HW_ + (size_t)(w >> 5) * 8192 + h * 32 + (w & 31);
        } else {
          off = pb + (size_t)o * HW_ + s; // natural [c][h][w]
        }
        dst[off] = (bf16_t)v;
      }
    }
  }
}

__global__ __launch_bounds__(256, 2) void conv_kernel(
    const float* __restrict__ x,
    const float* __restrict__ Wf, const float* __restrict__ bfp, const float* __restrict__ afp,
    const float* __restrict__ Wg, const float* __restrict__ bgp, const float* __restrict__ agp,
    const float* __restrict__ Wh, const float* __restrict__ bhp, const float* __restrict__ ahp,
    bf16_t* __restrict__ mF, bf16_t* __restrict__ mG, bf16_t* __restrict__ mH, int b0)
{
  __shared__ __align__(16) char lds[65536];
  const int t = threadIdx.x;
  const int bloc = blockIdx.y;
  const int s0 = blockIdx.x * 128;
  const size_t xbase = ((size_t)(b0 + bloc) * C_) * HW_ + s0;

  // stage x tile (128c x 128s) f32 -> transposed bf16 LDS [s][c]
  #pragma unroll
  for (int rep = 0; rep < 4; ++rep) {
    int q = rep * 256 + t;
    int c0 = (q >> 5) * 4, sl0 = (q & 31) * 4;
    f32x4 r[4];
    #pragma unroll
    for (int i = 0; i < 4; ++i)
      r[i] = *(const f32x4*)(x + xbase + (size_t)(c0 + i) * HW_ + sl0);
    #pragma unroll
    for (int js = 0; js < 4; ++js) {
      int s = sl0 + js;
      bf16x4 v;
      v[0] = (bf16_t)r[0][js]; v[1] = (bf16_t)r[1][js];
      v[2] = (bf16_t)r[2][js]; v[3] = (bf16_t)r[3][js];
      *(bf16x4*)(lds + ((s * 256 + c0 * 2) ^ swz(s))) = v;
    }
  }

  const int wv = t >> 6, lane = t & 63, lr = lane & 15, lq = lane >> 4;
  const size_t pb = (size_t)bloc * C_ * HW_;
  conv_one<false>(lds, Wf, bfp, afp[0], mF, pb, wv, lr, lq, t, s0);
  conv_one<false>(lds, Wg, bgp, agp[0], mG, pb, wv, lr, lq, t, s0);
  conv_one<true >(lds, Wh, bhp, ahp[0], mH, pb, wv, lr, lq, t, s0);
}

// =====================================================================
// Phase 2: 1024 thr / 16 waves, per (b,c) plane.
//  S phase : (wr4 x wc4) split, acc 64 f32/lane, reg-transpose staging,
//            raw barriers keep next-chunk prefetch in flight.
//  softmax : cross-wave combine via smax/ssum in DEDICATED region (no
//            overlay ordering barrier).
//  PV      : (wr16) split — wave owns 16 unique h-rows x all 256 v.
//            A = H direct from global (W32-blocked, 1KB contiguous wave
//            reads, each element fetched ONCE), 3-deep pipeline;
//            B = full PT[v=256][w=256] bf16 LDS; zero barriers in loop.
// LDS (139264 B): [0,64K) Ft|Gt chunks -> reused as PT [0,128K);
//                 smax f32[4][256] @128K, ssum @132K.
// =====================================================================
#define SMAX_OFF 131072
#define SSUM_OFF 135168
#define ATTN_SMEM 139264

__global__ __launch_bounds__(1024, 4) void attn_kernel(
    const bf16_t* __restrict__ mF, const bf16_t* __restrict__ mG, const bf16_t* __restrict__ mH,
    const float* __restrict__ x, float* __restrict__ out, int b0)
{
  extern __shared__ __align__(16) char smem[];
  const int t = threadIdx.x;
  const int c = blockIdx.x, bloc = blockIdx.y;
  const int lane = t & 63, lr = lane & 15, lq = lane >> 4;
  const int wv = t >> 6;
  const int wr4 = wv >> 2, wc4 = wv & 3;     // S-phase split
  const size_t plane  = ((size_t)bloc * C_ + c) * HW_;
  const size_t gplane = (((size_t)(b0 + bloc)) * C_ + c) * HW_;

  const f32x4 fz = {0.f, 0.f, 0.f, 0.f};
  f32x4 acc[4][4];
  #pragma unroll
  for (int mf = 0; mf < 4; ++mf)
    #pragma unroll
    for (int nf = 0; nf < 4; ++nf)
      acc[mf][nf] = fz;

  // ---- S = F^T G, 4 h-chunks of 64 ----
  const int sg = t >> 9;             // waves 0..7 stage F, 8..15 stage G
  const int u  = t & 511;
  const int w0 = (u & 31) * 8, h0 = (u >> 5) * 4;
  const bf16_t* sp = sg ? mG : mF;
  char* sd = smem + sg * 32768;

  bf16x8 pf[4];
  #pragma unroll
  for (int i = 0; i < 4; ++i)
    pf[i] = *(const bf16x8*)(sp + plane + (size_t)(h0 + i) * 256 + w0);

  #pragma unroll
  for (int hc = 0; hc < 4; ++hc) {
    #pragma unroll
    for (int j = 0; j < 8; ++j) {
      int w = w0 + j;
      bf16x4 v; v[0] = pf[0][j]; v[1] = pf[1][j]; v[2] = pf[2][j]; v[3] = pf[3][j];
      *(bf16x4*)(sd + ((w * 128 + h0 * 2) ^ swz(w))) = v;
    }
    if (hc < 3) {                    // prefetch next chunk; stays in flight across BAR
      #pragma unroll
      for (int i = 0; i < 4; ++i)
        pf[i] = *(const bf16x8*)(sp + plane + (size_t)((hc + 1) * 64 + h0 + i) * 256 + w0);
    }
    LGKM0(); BAR();
    #pragma unroll
    for (int k0 = 0; k0 < 64; k0 += 32) {
      const int kb = k0 + lq * 8;
      bf16x8 af[4], bq[4];
      #pragma unroll
      for (int mf = 0; mf < 4; ++mf) {
        int m = wr4 * 64 + mf * 16 + lr;
        af[mf] = *(const bf16x8*)(smem + ((m * 128 + kb * 2) ^ swz(m)));
      }
      #pragma unroll
      for (int nf = 0; nf < 4; ++nf) {
        int n = wc4 * 64 + nf * 16 + lr;
        bq[nf] = *(const bf16x8*)(smem + 32768 + ((n * 128 + kb * 2) ^ swz(n)));
      }
      #pragma unroll
      for (int mf = 0; mf < 4; ++mf)
        #pragma unroll
        for (int nf = 0; nf < 4; ++nf)
          acc[mf][nf] = __builtin_amdgcn_mfma_f32_16x16x32_bf16(af[mf], bq[nf], acc[mf][nf], 0, 0, 0);
    }
    BAR();
  }

  // ---- softmax over v (rows w) ----
  float* smax = (float*)(smem + SMAX_OFF);
  float* ssum = (float*)(smem + SSUM_OFF);
  float rinv[4][4];
  {
    float rowm[4][4];
    #pragma unroll
    for (int mf = 0; mf < 4; ++mf)
      #pragma unroll
      for (int i = 0; i < 4; ++i) {
        float m = fmaxf(fmaxf(acc[mf][0][i], acc[mf][1][i]),
                        fmaxf(acc[mf][2][i], acc[mf][3][i]));
        #pragma unroll
        for (int d = 1; d < 16; d <<= 1) m = fmaxf(m, __shfl_xor(m, d));
        rowm[mf][i] = m;
      }
    if (lr == 0) {
      #pragma unroll
      for (int mf = 0; mf < 4; ++mf)
        #pragma unroll
        for (int i = 0; i < 4; ++i)
          smax[wc4 * 256 + wr4 * 64 + mf * 16 + lq * 4 + i] = rowm[mf][i];
    }
    LGKM0(); BAR();
    #pragma unroll
    for (int mf = 0; mf < 4; ++mf)
      #pragma unroll
      for (int i = 0; i < 4; ++i) {
        int w = wr4 * 64 + mf * 16 + lq * 4 + i;
        rowm[mf][i] = fmaxf(fmaxf(smax[w], smax[256 + w]),
                            fmaxf(smax[512 + w], smax[768 + w]));
      }
    #pragma unroll
    for (int mf = 0; mf < 4; ++mf)
      #pragma unroll
      for (int i = 0; i < 4; ++i) {
        float rs = 0.f;
        #pragma unroll
        for (int nf = 0; nf < 4; ++nf) {
          float e = __expf(acc[mf][nf][i] - rowm[mf][i]);
          acc[mf][nf][i] = e;
          rs += e;
        }
        #pragma unroll
        for (int d = 1; d < 16; d <<= 1) rs += __shfl_xor(rs, d);
        if (lr == 0) ssum[wc4 * 256 + wr4 * 64 + mf * 16 + lq * 4 + i] = rs;
      }
    LGKM0(); BAR();
    #pragma unroll
    for (int mf = 0; mf < 4; ++mf)
      #pragma unroll
      for (int i = 0; i < 4; ++i) {
        int w = wr4 * 64 + mf * 16 + lq * 4 + i;
        rinv[mf][i] = 1.f / (ssum[w] + ssum[256 + w] + ssum[512 + w] + ssum[768 + w]);
      }
  }

  // ---- P -> bf16 -> PT[v][w] (smax/ssum live elsewhere: no extra BAR) ----
  #pragma unroll
  for (int mf = 0; mf < 4; ++mf) {
    int wpb = (wr4 * 64 + mf * 16 + lq * 4) * 2;
    #pragma unroll
    for (int nf = 0; nf < 4; ++nf) {
      int v_ = wc4 * 64 + nf * 16 + lr;
      bf16x4 v;
      #pragma unroll
      for (int i = 0; i < 4; ++i) v[i] = (bf16_t)(acc[mf][nf][i] * rinv[mf][i]);
      *(bf16x4*)(smem + ((v_ * 512 + wpb) ^ swz(v_))) = v;
    }
  }

  // ---- prefetch H chunks 0..2 (wave wv owns h rows [wv*16, wv*16+16)) ----
  const bf16_t* hp = mH + plane;
  const int ha = (wv * 16 + lr) * 32 + lq * 8;   // h-row base + k-offset in a W32 block
  bf16x8 aP[3];
  #pragma unroll
  for (int p = 0; p < 3; ++p)
    aP[p] = *(const bf16x8*)(hp + p * 8192 + ha);

  LGKM0(); BAR();  // PT visible to all; H prefetch stays in flight

  // ---- out = H*P: 8 w-chunks, H read once, no barriers ----
  f32x4 oac[16];
  #pragma unroll
  for (int nf = 0; nf < 16; ++nf) oac[nf] = fz;

  __builtin_amdgcn_s_setprio(1);
  #pragma unroll
  for (int kc = 0; kc < 8; ++kc) {
    bf16x8 av = aP[kc % 3];
    if (kc < 5)
      aP[kc % 3] = *(const bf16x8*)(hp + (size_t)(kc + 3) * 8192 + ha);
    #pragma unroll
    for (int nf = 0; nf < 16; ++nf) {
      int v_ = nf * 16 + lr;
      bf16x8 bq = *(const bf16x8*)(smem + ((v_ * 512 + kc * 64 + lq * 16) ^ swz(v_)));
      oac[nf] = __builtin_amdgcn_mfma_f32_16x16x32_bf16(av, bq, oac[nf], 0, 0, 0);
    }
  }
  __builtin_amdgcn_s_setprio(0);

  // ---- residual + store f32 (wave writes its 16 rows fully) ----
  #pragma unroll
  for (int i = 0; i < 4; ++i) {
    int h = wv * 16 + lq * 4 + i;
    #pragma unroll
    for (int nf = 0; nf < 16; ++nf) {
      int v_ = nf * 16 + lr;
      size_t off = gplane + (size_t)h * 256 + v_;
      out[off] = oac[nf][i] + x[off];
    }
  }
}

// =====================================================================
extern "C" void kernel_launch(void* const* d_in, const int* in_sizes, int n_in,
                              void* d_out, int out_size, void* d_ws, size_t ws_size,
                              hipStream_t stream)
{
  (void)in_sizes; (void)n_in; (void)out_size;
  const float* x   = (const float*)d_in[0];
  const float* Wf  = (const float*)d_in[1];
  const float* bfp = (const float*)d_in[2];
  const float* afp = (const float*)d_in[3];
  const float* Wg  = (const float*)d_in[4];
  const float* bgp = (const float*)d_in[5];
  const float* agp = (const float*)d_in[6];
  const float* Wh  = (const float*)d_in[7];
  const float* bhp = (const float*)d_in[8];
  const float* ahp = (const float*)d_in[9];
  float* out = (float*)d_out;

  const size_t per_map_b = (size_t)C_ * HW_ * sizeof(bf16_t);  // 16 MiB per map per batch
  // nb=4 keeps the 3 maps (192 MB) inside the 256 MB Infinity Cache so the
  // attn pass reads them from L3, not HBM.  (nb=8 would be 384 MB > L3.)
  int nb = 1;
  if      (ws_size >= 3 * 4 * per_map_b) nb = 4;
  else if (ws_size >= 3 * 2 * per_map_b) nb = 2;

  hipFuncSetAttribute(reinterpret_cast<const void*>(attn_kernel),
                      hipFuncAttributeMaxDynamicSharedMemorySize, ATTN_SMEM);

  bf16_t* mF = (bf16_t*)d_ws;
  bf16_t* mG = mF + (size_t)nb * C_ * HW_;
  bf16_t* mH = mG + (size_t)nb * C_ * HW_;

  for (int b0 = 0; b0 < 8; b0 += nb) {
    conv_kernel<<<dim3(512, nb), 256, 0, stream>>>(x, Wf, bfp, afp, Wg, bgp, agp,
                                                   Wh, bhp, ahp, mF, mG, mH, b0);
    attn_kernel<<<dim3(C_, nb), 1024, ATTN_SMEM, stream>>>(mF, mG, mH, x, out, b0);
  }
}